// Round 4
// baseline (1381.936 us; speedup 1.0000x reference)
//
#include <hip/hip_runtime.h>
#include <hip/hip_bf16.h>

// Grid LSTM (tanh grid-RNN), D=2, S=T=48, B=32, H=256. f32 in/out; bf16 MFMA
// internally. Persistent systolic columns, one block per (d, t) walking s.
// v5: the left-neighbor handoff ships P = hx@Uy (pre-multiplied, f32, in the
// consumer's per-thread accumulator layout) as epoch-tagged 16B packets:
//  - producer: after refreshing its LDS up-image (bf16 hx), ONE fused 8-ks
//    MFMA pass computes next-cell up@Ux AND neighbor P = hx@Uy from the same
//    ds_reads. P is stored as 6 x global_store_dwordx4 sc0 sc1 per thread,
//    dword3 of each packet = epoch (s+1). No drain, no flag on the chain
//    (an off-chain vmcnt(0) protects the data VGPRs).
//  - consumer: polls its own 6 packets with global_load_dwordx4 sc0 sc1
//    (aligned 16B = single transaction: epoch match => payload valid). The
//    detect load IS the data load; adds into accT in registers. No cvt, no
//    LDS, no barrier, no MFMA on the receive side.
//  - depth-4 ring per producer column, back-pressured by per-wave acks
//    (consumer wave stores epoch after consuming; producer checks its ack
//    >= s-3 at cell start). Acyclic; steady-state non-blocking.
//  - layer0 -> layer1 x/y planes keep the v4 protocol (bypass f32 stores,
//    vmcnt drain, relaxed flag add; plain cached consumer loads, each
//    address read once per launch), placed AFTER the P store (off-chain).
//  - hx1/hy1 have no in-kernel consumers -> plain cached stores; FLAG1 gone.

typedef short short8 __attribute__((ext_vector_type(8)));
typedef float f32x4 __attribute__((ext_vector_type(4)));
typedef int   i32x4 __attribute__((ext_vector_type(4)));

static constexpr size_t UF_OFF    = 0;                           // 512 KiB U frags (bf16)
static constexpr size_t WF_OFF    = 512u * 1024;                 // 256 KiB W frags (bf16)
static constexpr size_t SRCW_OFF  = 768u * 1024;                 // 1.5 MiB f32 (acc layout)
static constexpr size_t TRGW_OFF  = SRCW_OFF + 48u * 32 * 256 * 4;
static constexpr size_t FLAG0_OFF = TRGW_OFF + 48u * 32 * 256 * 4;   // 48*48 x 128B
static constexpr size_t P0_OFF    = FLAG0_OFF + 48u * 48 * 128;      // 48 t x 4 slots x 48KB
static constexpr size_t P1_OFF    = P0_OFF + 48u * 4 * 49152;
static constexpr size_t ACK0_OFF  = P1_OFF + 48u * 4 * 49152;        // 48 t x 8 waves x 128B
static constexpr size_t ACK1_OFF  = ACK0_OFF + 48u * 8 * 128;
static constexpr size_t WS_END    = ACK1_OFF + 48u * 8 * 128;        // ~23.2 MiB

#define MFMA16(a, b, c) __builtin_amdgcn_mfma_f32_16x16x32_bf16(a, b, c, 0, 0, 0)

__device__ __forceinline__ short f2bf(float f) {
  __hip_bfloat16 h = __float2bfloat16(f);
  return __builtin_bit_cast(short, h);
}

__device__ __forceinline__ size_t plane_off(int d, int s, int t, int c) {
  return (size_t)(((d * 48 + s) * 48 + t) * 2 + c) * 8192u;  // f32 elements
}

__device__ __forceinline__ void wait_ge(int* p, int v) {
  while (__hip_atomic_load(p, __ATOMIC_RELAXED, __HIP_MEMORY_SCOPE_AGENT) < v)
    __builtin_amdgcn_s_sleep(1);
  asm volatile("" ::: "memory");
}

// write-through to LLC (sc0 sc1): visible agent-wide once vmcnt retires.
__device__ __forceinline__ void st_llc(float* p, float v) {
  __hip_atomic_store(p, v, __ATOMIC_RELAXED, __HIP_MEMORY_SCOPE_AGENT);
}
__device__ __forceinline__ void st_llc_i(int* p, int v) {
  __hip_atomic_store(p, v, __ATOMIC_RELAXED, __HIP_MEMORY_SCOPE_AGENT);
}

__device__ __forceinline__ float fast_tanh(float x) {
  float e = exp2f(x * 2.88539008f);
  return 1.f - __fdividef(2.f, e + 1.f);
}

// ---------------------------------------------------------------------------
// Kernel 1: U (2,512,256) f32 and W (2,256,256) f32 -> bf16 MFMA B-fragments.
// ---------------------------------------------------------------------------
__global__ void preswizzle(const float* __restrict__ U,
                           const float* __restrict__ W,
                           char* __restrict__ ws) {
  int gid = blockIdx.x * 256 + threadIdx.x;
  if (gid < 32768) {  // U
    int r = gid >> 11;
    int d = r >> 3, nh = (r >> 2) & 1, w = r & 3;
    int c = gid & 2047;
    int f = c >> 6, lane = c & 63;
    int nt = f >> 4, ks = f & 15;
    int kbase = ks * 32 + (lane >> 4) * 8;
    int n = nh * 128 + w * 32 + nt * 16 + (lane & 15);
    const float* sp = U + (size_t)d * 512 * 256 + n;
    short8 v;
#pragma unroll
    for (int j = 0; j < 8; ++j) v[j] = f2bf(sp[(size_t)(kbase + j) * 256]);
    *(short8*)(ws + UF_OFF + (size_t)gid * 16) = v;
  } else {            // W
    int idx = gid - 32768;
    int r = idx >> 10;
    int d = r >> 3, nh = (r >> 2) & 1, w = r & 3;
    int c = idx & 1023;
    int f = c >> 6, lane = c & 63;
    int nt = f >> 3, ks = f & 7;
    int kbase = ks * 32 + (lane >> 4) * 8;
    int n = nh * 128 + w * 32 + nt * 16 + (lane & 15);
    const float* sp = W + (size_t)d * 256 * 256 + n;
    short8 v;
#pragma unroll
    for (int j = 0; j < 8; ++j) v[j] = f2bf(sp[(size_t)(kbase + j) * 256]);
    *(short8*)(ws + WF_OFF + (size_t)idx * 16) = v;
  }
}

// ---------------------------------------------------------------------------
// Kernel 2: SRCW[s] = src[s]@W0 + b0 ; TRGW[t] = trg[t]@W0 + b0  (f32),
// stored in grid_main's per-thread accumulator layout: [i][gtid][16].
// ---------------------------------------------------------------------------
__global__ __launch_bounds__(256, 1) void precompute_xw(
    const float* __restrict__ src, const float* __restrict__ trg,
    const float* __restrict__ bvec, char* __restrict__ ws) {
  __shared__ __align__(16) char lds[32 * 528];
  const int bid = blockIdx.x;
  const int i = bid >> 1, nh = bid & 1;
  const int tid = threadIdx.x;
  const int w = tid >> 6, lane = tid & 63;
  const int alane = lane & 15, q = lane >> 4;

  short8 bw[2][8];
  {
    const char* wb = ws + WF_OFF + (size_t)(nh * 4 + w) * 16384u + (size_t)lane * 16;
#pragma unroll
    for (int nt = 0; nt < 2; ++nt)
#pragma unroll
      for (int ks = 0; ks < 8; ++ks)
        bw[nt][ks] = *(const short8*)(wb + (nt * 8 + ks) * 1024);
  }

  const float* plane = (i < 48) ? src + (size_t)i * 8192 : trg + (size_t)(i - 48) * 8192;
#pragma unroll
  for (int it = 0; it < 4; ++it) {
    int gid = it * 256 + tid;
    int row = gid >> 5, c = gid & 31;
    const float* p = plane + row * 256 + c * 8;
    short8 v;
#pragma unroll
    for (int j = 0; j < 8; ++j) v[j] = f2bf(p[j]);
    *(short8*)(lds + row * 528 + c * 16) = v;
  }
  __syncthreads();

  const f32x4 zf = {0.f, 0.f, 0.f, 0.f};
  f32x4 acc[2][2];
  acc[0][0] = zf; acc[0][1] = zf; acc[1][0] = zf; acc[1][1] = zf;
  const char* ar0 = lds + alane * 528 + q * 16;
  const char* ar1 = lds + (alane + 16) * 528 + q * 16;
#pragma unroll
  for (int ks = 0; ks < 8; ++ks) {
    short8 a0 = *(const short8*)(ar0 + ks * 64);
    short8 a1 = *(const short8*)(ar1 + ks * 64);
#pragma unroll
    for (int nt = 0; nt < 2; ++nt) {
      acc[0][nt] = MFMA16(a0, bw[nt][ks], acc[0][nt]);
      acc[1][nt] = MFMA16(a1, bw[nt][ks], acc[1][nt]);
    }
  }

  const int n0 = nh * 128 + w * 32 + alane;
  float bs[2] = {bvec[n0], bvec[n0 + 16]};
  const int gtid = (nh * 4 + w) * 64 + lane;
  float* dst = (float*)(ws + (i < 48 ? SRCW_OFF : TRGW_OFF)) +
               (size_t)(i < 48 ? i : i - 48) * 8192 + (size_t)gtid * 16;
#pragma unroll
  for (int mt = 0; mt < 2; ++mt)
#pragma unroll
    for (int nt = 0; nt < 2; ++nt) {
      f32x4 v = acc[mt][nt];
      v[0] += bs[nt]; v[1] += bs[nt]; v[2] += bs[nt]; v[3] += bs[nt];
      ((f32x4*)dst)[mt * 2 + nt] = v;
    }
}

// ---------------------------------------------------------------------------
// Kernel 3: persistent systolic grid. 96 blocks x 512 threads = (d, t).
// ---------------------------------------------------------------------------
__global__ __launch_bounds__(512, 1) void grid_main(
    float* __restrict__ out, const float* __restrict__ bvec,
    char* __restrict__ ws) {
  // buf0 = persistent up-image (bf16, A-frag layout); buf1/buf2 = layer-1 x/y.
  __shared__ __align__(16) char lds[3 * 32 * 528];
  char* const buf0 = lds;
  char* const buf1 = lds + 32 * 528;
  char* const buf2 = lds + 2 * 32 * 528;

  const int bid = blockIdx.x;        // 96 = (d, t)
  const int d = bid / 48;
  const int t = bid % 48;
  const int tid = threadIdx.x;       // 0..511
  const int wv = tid >> 6;           // 0..7
  const int nh = wv >> 2, w = wv & 3;
  const int lane = tid & 63;
  const int alane = lane & 15, q = lane >> 4;
  const int n0 = nh * 128 + w * 32 + alane;

  const float* SRCW = (const float*)(ws + SRCW_OFF);
  const float* TRGW = (const float*)(ws + TRGW_OFF);
  const size_t POFF = d ? P1_OFF : P0_OFF;
  int* const ACK = (int*)(ws + (d ? ACK1_OFF : ACK0_OFF));

  // U B-frags in registers: bu[nt][ks]; ks 0..7 = Ux (up), 8..15 = Uy (left)
  short8 bu[2][16];
  {
    const char* ub = ws + UF_OFF + (size_t)((d * 2 + nh) * 4 + w) * 32768u +
                     (size_t)lane * 16;
#pragma unroll
    for (int nt = 0; nt < 2; ++nt)
#pragma unroll
      for (int ks = 0; ks < 16; ++ks)
        bu[nt][ks] = *(const short8*)(ub + (nt * 16 + ks) * 1024);
  }

  const char* up0 = buf0 + alane * 528 + q * 16;
  const char* up1 = buf0 + (alane + 16) * 528 + q * 16;
  const char* x0  = buf1 + alane * 528 + q * 16;
  const char* x1  = buf1 + (alane + 16) * 528 + q * 16;
  const char* y0  = buf2 + alane * 528 + q * 16;
  const char* y1  = buf2 + (alane + 16) * 528 + q * 16;
  const f32x4 zf = {0.f, 0.f, 0.f, 0.f};

  f32x4 accTup[2][2];  // up@Ux carried from previous cell's fused pass
  accTup[0][0] = zf; accTup[0][1] = zf; accTup[1][0] = zf; accTup[1][1] = zf;

  __syncthreads();

  if (d == 0) {
    f32x4 pfy[4];
    {
      const f32x4* py = (const f32x4*)(TRGW + (size_t)t * 8192 + (size_t)tid * 16);
      pfy[0] = py[0]; pfy[1] = py[1]; pfy[2] = py[2]; pfy[3] = py[3];
    }
    for (int s = 0; s < 48; ++s) {
      // C-init loads (ws-hot, issued before the poll)
      f32x4 sxv[4];
      {
        const f32x4* px = (const f32x4*)(SRCW + (size_t)s * 8192 + (size_t)tid * 16);
        sxv[0] = px[0]; sxv[1] = px[1]; sxv[2] = px[2]; sxv[3] = px[3];
      }
      // ring back-pressure: my right neighbor must have consumed slot s&3
      if (t < 47 && s >= 4) wait_ge(ACK + (t * 8 + wv) * 32, s - 3);

      // ---- receive P = left@Uy (epoch-tagged packets, direct to regs) ----
      float pv[16];
      if (t > 0) {
        const char* pb = ws + POFF + ((size_t)(t - 1) * 4 + (size_t)(s & 3)) * 49152u +
                         (size_t)tid * 96u;
        const int want = s + 1;
        f32x4 k0, k1, k2, k3, k4, k5;
        for (;;) {
          asm volatile(
              "global_load_dwordx4 %0, %6, off sc0 sc1\n\t"
              "global_load_dwordx4 %1, %6, off offset:16 sc0 sc1\n\t"
              "global_load_dwordx4 %2, %6, off offset:32 sc0 sc1\n\t"
              "global_load_dwordx4 %3, %6, off offset:48 sc0 sc1\n\t"
              "global_load_dwordx4 %4, %6, off offset:64 sc0 sc1\n\t"
              "global_load_dwordx4 %5, %6, off offset:80 sc0 sc1\n\t"
              "s_waitcnt vmcnt(0)"
              : "=v"(k0), "=v"(k1), "=v"(k2), "=v"(k3), "=v"(k4), "=v"(k5)
              : "v"(pb)
              : "memory");
          __builtin_amdgcn_sched_barrier(0);
          i32x4 e0 = __builtin_bit_cast(i32x4, k0), e1 = __builtin_bit_cast(i32x4, k1),
                e2 = __builtin_bit_cast(i32x4, k2), e3 = __builtin_bit_cast(i32x4, k3),
                e4 = __builtin_bit_cast(i32x4, k4), e5 = __builtin_bit_cast(i32x4, k5);
          if (e0.w == want && e1.w == want && e2.w == want &&
              e3.w == want && e4.w == want && e5.w == want) break;
          __builtin_amdgcn_s_sleep(1);
        }
        pv[0] = k0.x;  pv[1] = k0.y;  pv[2] = k0.z;
        pv[3] = k1.x;  pv[4] = k1.y;  pv[5] = k1.z;
        pv[6] = k2.x;  pv[7] = k2.y;  pv[8] = k2.z;
        pv[9] = k3.x;  pv[10] = k3.y; pv[11] = k3.z;
        pv[12] = k4.x; pv[13] = k4.y; pv[14] = k4.z;
        pv[15] = k5.x;
        if (lane == 0) st_llc_i(ACK + ((t - 1) * 8 + wv) * 32, s + 1);
      } else {
#pragma unroll
        for (int i = 0; i < 16; ++i) pv[i] = 0.f;
      }

      // accT = up@Ux (carried) + P ; hx = tanh(xw + accT)
      f32x4 accT[2][2];
      float hxv[16];
#pragma unroll
      for (int mt = 0; mt < 2; ++mt)
#pragma unroll
        for (int nt = 0; nt < 2; ++nt)
#pragma unroll
          for (int rr = 0; rr < 4; ++rr) {
            int i = (mt * 2 + nt) * 4 + rr;
            float tv = accTup[mt][nt][rr] + pv[i];
            accT[mt][nt][rr] = tv;
            hxv[i] = fast_tanh(sxv[mt * 2 + nt][rr] + tv);
          }
      __syncthreads();  // B1: all waves done with buf0(s-1) (prev fused pass)
#pragma unroll
      for (int mt = 0; mt < 2; ++mt)
#pragma unroll
        for (int nt = 0; nt < 2; ++nt)
#pragma unroll
          for (int rr = 0; rr < 4; ++rr) {
            int row = mt * 16 + q * 4 + rr, c = n0 + nt * 16;
            *(short*)(buf0 + row * 528 + c * 2) = f2bf(hxv[(mt * 2 + nt) * 4 + rr]);
          }
      __syncthreads();  // B2: up-image(s) ready

      // ---- fused pass: P(s) = hx@Uy and next-up = hx@Ux, one ds_read sweep
      f32x4 accP[2][2];
      accP[0][0] = zf; accP[0][1] = zf; accP[1][0] = zf; accP[1][1] = zf;
      accTup[0][0] = zf; accTup[0][1] = zf; accTup[1][0] = zf; accTup[1][1] = zf;
#pragma unroll
      for (int ks = 0; ks < 8; ++ks) {
        short8 a0 = *(const short8*)(up0 + ks * 64);
        short8 a1 = *(const short8*)(up1 + ks * 64);
        accTup[0][0] = MFMA16(a0, bu[0][ks], accTup[0][0]);
        accTup[0][1] = MFMA16(a0, bu[1][ks], accTup[0][1]);
        accTup[1][0] = MFMA16(a1, bu[0][ks], accTup[1][0]);
        accTup[1][1] = MFMA16(a1, bu[1][ks], accTup[1][1]);
        accP[0][0] = MFMA16(a0, bu[0][8 + ks], accP[0][0]);
        accP[0][1] = MFMA16(a0, bu[1][8 + ks], accP[0][1]);
        accP[1][0] = MFMA16(a1, bu[0][8 + ks], accP[1][0]);
        accP[1][1] = MFMA16(a1, bu[1][8 + ks], accP[1][1]);
      }
      // ---- ship P packets (epoch = s+1); local vmcnt protects data VGPRs
      if (t < 47) {
        float pp[16];
#pragma unroll
        for (int mt = 0; mt < 2; ++mt)
#pragma unroll
          for (int nt = 0; nt < 2; ++nt)
#pragma unroll
            for (int rr = 0; rr < 4; ++rr)
              pp[(mt * 2 + nt) * 4 + rr] = accP[mt][nt][rr];
        const float ef = __builtin_bit_cast(float, s + 1);
        f32x4 q0 = {pp[0], pp[1], pp[2], ef},  q1 = {pp[3], pp[4], pp[5], ef};
        f32x4 q2 = {pp[6], pp[7], pp[8], ef},  q3 = {pp[9], pp[10], pp[11], ef};
        f32x4 q4 = {pp[12], pp[13], pp[14], ef}, q5 = {pp[15], ef, ef, ef};
        char* qb = ws + POFF + ((size_t)t * 4 + (size_t)(s & 3)) * 49152u +
                   (size_t)tid * 96u;
        asm volatile(
            "global_store_dwordx4 %6, %0, off sc0 sc1\n\t"
            "global_store_dwordx4 %6, %1, off offset:16 sc0 sc1\n\t"
            "global_store_dwordx4 %6, %2, off offset:32 sc0 sc1\n\t"
            "global_store_dwordx4 %6, %3, off offset:48 sc0 sc1\n\t"
            "global_store_dwordx4 %6, %4, off offset:64 sc0 sc1\n\t"
            "global_store_dwordx4 %6, %5, off offset:80 sc0 sc1\n\t"
            "s_waitcnt vmcnt(0)"
            :: "v"(q0), "v"(q1), "v"(q2), "v"(q3), "v"(q4), "v"(q5), "v"(qb)
            : "memory");
      }
      // ---- hy + f32 outputs (bypass; consumed by layer 1 via flagB0) ----
      {
        float* hxp = out + plane_off(0, s, t, 0);
        float* hyp = out + plane_off(0, s, t, 1);
#pragma unroll
        for (int mt = 0; mt < 2; ++mt)
#pragma unroll
          for (int nt = 0; nt < 2; ++nt)
#pragma unroll
            for (int rr = 0; rr < 4; ++rr) {
              int i = (mt * 2 + nt) * 4 + rr;
              int row = mt * 16 + q * 4 + rr, c = n0 + nt * 16;
              float yv = fast_tanh(pfy[mt * 2 + nt][rr] + accT[mt][nt][rr]);
              st_llc(&hxp[row * 256 + c], hxv[i]);
              st_llc(&hyp[row * 256 + c], yv);
            }
      }
      asm volatile("s_waitcnt vmcnt(0)" ::: "memory");
      if (lane == 0)
        __hip_atomic_fetch_add((int*)(ws + FLAG0_OFF) + (size_t)(s * 48 + t) * 32, 1,
                               __ATOMIC_RELAXED, __HIP_MEMORY_SCOPE_AGENT);
    }
  } else {
    // ---- layer 1 ----
    const char* wbp = ws + WF_OFF + (size_t)((2 + nh) * 4 + w) * 16384u +
                      (size_t)lane * 16;
    const float bsa = bvec[256 + n0], bsb = bvec[256 + n0 + 16];
    const f32x4 bA = {bsa, bsa, bsa, bsa};
    const f32x4 bB = {bsb, bsb, bsb, bsb};
    for (int s = 0; s < 48; ++s) {
      if (t < 47 && s >= 4) wait_ge(ACK + (t * 8 + wv) * 32, s - 3);
      // x/y planes from layer 0 (flag usually long-set; plain cached loads)
      wait_ge((int*)(ws + FLAG0_OFF) + (size_t)(s * 48 + t) * 32, 8);
      f32x4 xva[4], xvb[4];
      {
        const float* px = out + plane_off(0, s, t, 0);
        const float* py = out + plane_off(0, s, t, 1);
#pragma unroll
        for (int it = 0; it < 4; ++it) {
          int gid = it * 512 + tid;
          int pidx = gid >> 10, row = (gid >> 5) & 31, c = gid & 31;
          const float* pp = (pidx ? py : px) + row * 256 + c * 8;
          xva[it] = *(const f32x4*)pp;
          xvb[it] = *(const f32x4*)(pp + 4);
        }
      }
#pragma unroll
      for (int it = 0; it < 4; ++it) {
        int gid = it * 512 + tid;
        int pidx = gid >> 10, row = (gid >> 5) & 31, c = gid & 31;
        char* db = pidx ? buf2 : buf1;
        short8 v;
#pragma unroll
        for (int j = 0; j < 4; ++j) {
          v[j] = f2bf(xva[it][j]);
          v[4 + j] = f2bf(xvb[it][j]);
        }
        *(short8*)(db + row * 528 + c * 16) = v;
      }
      __syncthreads();  // Bxy: x/y staged
      f32x4 accx[2][2], accy[2][2];
      accx[0][0] = bA; accx[0][1] = bB; accx[1][0] = bA; accx[1][1] = bB;
      accy[0][0] = bA; accy[0][1] = bB; accy[1][0] = bA; accy[1][1] = bB;
#pragma unroll
      for (int ks = 0; ks < 8; ++ks) {
        short8 b0 = *(const short8*)(wbp + ks * 1024);
        short8 b1 = *(const short8*)(wbp + (8 + ks) * 1024);
        short8 ax0 = *(const short8*)(x0 + ks * 64);
        short8 ax1 = *(const short8*)(x1 + ks * 64);
        short8 ay0 = *(const short8*)(y0 + ks * 64);
        short8 ay1 = *(const short8*)(y1 + ks * 64);
        accx[0][0] = MFMA16(ax0, b0, accx[0][0]);
        accx[0][1] = MFMA16(ax0, b1, accx[0][1]);
        accx[1][0] = MFMA16(ax1, b0, accx[1][0]);
        accx[1][1] = MFMA16(ax1, b1, accx[1][1]);
        accy[0][0] = MFMA16(ay0, b0, accy[0][0]);
        accy[0][1] = MFMA16(ay0, b1, accy[0][1]);
        accy[1][0] = MFMA16(ay1, b0, accy[1][0]);
        accy[1][1] = MFMA16(ay1, b1, accy[1][1]);
      }
      // ---- receive P1 ----
      float pv[16];
      if (t > 0) {
        const char* pb = ws + POFF + ((size_t)(t - 1) * 4 + (size_t)(s & 3)) * 49152u +
                         (size_t)tid * 96u;
        const int want = s + 1;
        f32x4 k0, k1, k2, k3, k4, k5;
        for (;;) {
          asm volatile(
              "global_load_dwordx4 %0, %6, off sc0 sc1\n\t"
              "global_load_dwordx4 %1, %6, off offset:16 sc0 sc1\n\t"
              "global_load_dwordx4 %2, %6, off offset:32 sc0 sc1\n\t"
              "global_load_dwordx4 %3, %6, off offset:48 sc0 sc1\n\t"
              "global_load_dwordx4 %4, %6, off offset:64 sc0 sc1\n\t"
              "global_load_dwordx4 %5, %6, off offset:80 sc0 sc1\n\t"
              "s_waitcnt vmcnt(0)"
              : "=v"(k0), "=v"(k1), "=v"(k2), "=v"(k3), "=v"(k4), "=v"(k5)
              : "v"(pb)
              : "memory");
          __builtin_amdgcn_sched_barrier(0);
          i32x4 e0 = __builtin_bit_cast(i32x4, k0), e1 = __builtin_bit_cast(i32x4, k1),
                e2 = __builtin_bit_cast(i32x4, k2), e3 = __builtin_bit_cast(i32x4, k3),
                e4 = __builtin_bit_cast(i32x4, k4), e5 = __builtin_bit_cast(i32x4, k5);
          if (e0.w == want && e1.w == want && e2.w == want &&
              e3.w == want && e4.w == want && e5.w == want) break;
          __builtin_amdgcn_s_sleep(1);
        }
        pv[0] = k0.x;  pv[1] = k0.y;  pv[2] = k0.z;
        pv[3] = k1.x;  pv[4] = k1.y;  pv[5] = k1.z;
        pv[6] = k2.x;  pv[7] = k2.y;  pv[8] = k2.z;
        pv[9] = k3.x;  pv[10] = k3.y; pv[11] = k3.z;
        pv[12] = k4.x; pv[13] = k4.y; pv[14] = k4.z;
        pv[15] = k5.x;
        if (lane == 0) st_llc_i(ACK + ((t - 1) * 8 + wv) * 32, s + 1);
      } else {
#pragma unroll
        for (int i = 0; i < 16; ++i) pv[i] = 0.f;
      }

      f32x4 accT[2][2];
      float hxv[16];
#pragma unroll
      for (int mt = 0; mt < 2; ++mt)
#pragma unroll
        for (int nt = 0; nt < 2; ++nt)
#pragma unroll
          for (int rr = 0; rr < 4; ++rr) {
            int i = (mt * 2 + nt) * 4 + rr;
            float tv = accTup[mt][nt][rr] + pv[i];
            accT[mt][nt][rr] = tv;
            hxv[i] = fast_tanh(accx[mt][nt][rr] + tv);
          }
      __syncthreads();  // B1
#pragma unroll
      for (int mt = 0; mt < 2; ++mt)
#pragma unroll
        for (int nt = 0; nt < 2; ++nt)
#pragma unroll
          for (int rr = 0; rr < 4; ++rr) {
            int row = mt * 16 + q * 4 + rr, c = n0 + nt * 16;
            *(short*)(buf0 + row * 528 + c * 2) = f2bf(hxv[(mt * 2 + nt) * 4 + rr]);
          }
      __syncthreads();  // B2
      f32x4 accP[2][2];
      accP[0][0] = zf; accP[0][1] = zf; accP[1][0] = zf; accP[1][1] = zf;
      accTup[0][0] = zf; accTup[0][1] = zf; accTup[1][0] = zf; accTup[1][1] = zf;
#pragma unroll
      for (int ks = 0; ks < 8; ++ks) {
        short8 a0 = *(const short8*)(up0 + ks * 64);
        short8 a1 = *(const short8*)(up1 + ks * 64);
        accTup[0][0] = MFMA16(a0, bu[0][ks], accTup[0][0]);
        accTup[0][1] = MFMA16(a0, bu[1][ks], accTup[0][1]);
        accTup[1][0] = MFMA16(a1, bu[0][ks], accTup[1][0]);
        accTup[1][1] = MFMA16(a1, bu[1][ks], accTup[1][1]);
        accP[0][0] = MFMA16(a0, bu[0][8 + ks], accP[0][0]);
        accP[0][1] = MFMA16(a0, bu[1][8 + ks], accP[0][1]);
        accP[1][0] = MFMA16(a1, bu[0][8 + ks], accP[1][0]);
        accP[1][1] = MFMA16(a1, bu[1][8 + ks], accP[1][1]);
      }
      if (t < 47) {
        float pp[16];
#pragma unroll
        for (int mt = 0; mt < 2; ++mt)
#pragma unroll
          for (int nt = 0; nt < 2; ++nt)
#pragma unroll
            for (int rr = 0; rr < 4; ++rr)
              pp[(mt * 2 + nt) * 4 + rr] = accP[mt][nt][rr];
        const float ef = __builtin_bit_cast(float, s + 1);
        f32x4 q0 = {pp[0], pp[1], pp[2], ef},  q1 = {pp[3], pp[4], pp[5], ef};
        f32x4 q2 = {pp[6], pp[7], pp[8], ef},  q3 = {pp[9], pp[10], pp[11], ef};
        f32x4 q4 = {pp[12], pp[13], pp[14], ef}, q5 = {pp[15], ef, ef, ef};
        char* qb = ws + POFF + ((size_t)t * 4 + (size_t)(s & 3)) * 49152u +
                   (size_t)tid * 96u;
        asm volatile(
            "global_store_dwordx4 %6, %0, off sc0 sc1\n\t"
            "global_store_dwordx4 %6, %1, off offset:16 sc0 sc1\n\t"
            "global_store_dwordx4 %6, %2, off offset:32 sc0 sc1\n\t"
            "global_store_dwordx4 %6, %3, off offset:48 sc0 sc1\n\t"
            "global_store_dwordx4 %6, %4, off offset:64 sc0 sc1\n\t"
            "global_store_dwordx4 %6, %5, off offset:80 sc0 sc1\n\t"
            "s_waitcnt vmcnt(0)"
            :: "v"(q0), "v"(q1), "v"(q2), "v"(q3), "v"(q4), "v"(q5), "v"(qb)
            : "memory");
      }
      // final outputs: no in-kernel consumers -> plain cached stores
      {
        float* hxp = out + plane_off(1, s, t, 0);
        float* hyp = out + plane_off(1, s, t, 1);
#pragma unroll
        for (int mt = 0; mt < 2; ++mt)
#pragma unroll
          for (int nt = 0; nt < 2; ++nt)
#pragma unroll
            for (int rr = 0; rr < 4; ++rr) {
              int i = (mt * 2 + nt) * 4 + rr;
              int row = mt * 16 + q * 4 + rr, c = n0 + nt * 16;
              hxp[row * 256 + c] = hxv[i];
              hyp[row * 256 + c] = fast_tanh(accy[mt][nt][rr] + accT[mt][nt][rr]);
            }
      }
    }
  }
}

extern "C" void kernel_launch(void* const* d_in, const int* in_sizes, int n_in,
                              void* d_out, int out_size, void* d_ws, size_t ws_size,
                              hipStream_t stream) {
  const float* src = (const float*)d_in[0];
  const float* trg = (const float*)d_in[1];
  const float* W   = (const float*)d_in[2];
  const float* U   = (const float*)d_in[3];
  const float* bv  = (const float*)d_in[4];
  float* out = (float*)d_out;
  char* ws = (char*)d_ws;

  // zero flags + P rings + acks in one shot (epoch 0 never matches s+1>=1)
  hipMemsetAsync(ws + FLAG0_OFF, 0, WS_END - FLAG0_OFF, stream);
  preswizzle<<<192, 256, 0, stream>>>(U, W, ws);
  precompute_xw<<<192, 256, 0, stream>>>(src, trg, bv, ws);
  grid_main<<<96, 512, 0, stream>>>(out, bv, ws);
}

// Round 5
// 822.914 us; speedup vs baseline: 1.6793x; 1.6793x over previous
//
#include <hip/hip_runtime.h>
#include <hip/hip_bf16.h>

// Grid LSTM (tanh grid-RNN), D=2, S=T=48, B=32, H=256. f32 in/out; bf16 MFMA
// internally. Persistent systolic columns, one block per (d, t) walking s.
// v6 = v4 transport (bypass f32 st_llc -> LLC, vmcnt drain, relaxed flag add;
// consumer polls relaxed + plain cached loads, each address read once per
// block per launch) + poll-window deferral:
//  - everything not gating a dependency (hy tanh/stores/drain/flagB, SRCW
//    loads, the up@Ux MFMA pass) runs in the NEXT cell's poll window, where
//    the block idles waiting for its left neighbor anyway.
//  - fused carry: after refreshing the LDS up-image (bf16 hx), compute
//    accTup = hx@Ux for the NEXT cell (window work). Post-detect critical
//    path: left load -> cvt/LDS -> barrier -> left-MFMA -> tanh -> hx
//    st_llc -> drain -> flagA -> buf0 refresh. (~2us target)
//  - buL[2][8] (Uy fragments, 64 VGPRs) asm-pinned in registers (they sit on
//    the post-detect path); Ux fragments stream from L2 in the window.
//    amdgpu_waves_per_eu(1,2) raises the VGPR budget to 256.
//  - flagB in its own cache lines; flag zeroing fused into preswizzle.

typedef short short8 __attribute__((ext_vector_type(8)));
typedef float f32x4 __attribute__((ext_vector_type(4)));

static constexpr size_t UF_OFF     = 0;                          // 512 KiB U frags (bf16)
static constexpr size_t WF_OFF     = 512u * 1024;                // 256 KiB W frags (bf16)
static constexpr size_t SRCW_OFF   = 768u * 1024;                // 1.5 MiB f32 (acc layout)
static constexpr size_t TRGW_OFF   = SRCW_OFF + 48u * 32 * 256 * 4;
static constexpr size_t FLAGA0_OFF = TRGW_OFF + 48u * 32 * 256 * 4;  // 48*48 x 128B each
static constexpr size_t FLAGB0_OFF = FLAGA0_OFF + 48u * 48 * 128;
static constexpr size_t FLAGA1_OFF = FLAGB0_OFF + 48u * 48 * 128;
static constexpr size_t FLAG_BYTES = 3u * 48 * 48 * 128;

#define MFMA16(a, b, c) __builtin_amdgcn_mfma_f32_16x16x32_bf16(a, b, c, 0, 0, 0)

__device__ __forceinline__ short f2bf(float f) {
  __hip_bfloat16 h = __float2bfloat16(f);
  return __builtin_bit_cast(short, h);
}

__device__ __forceinline__ size_t plane_off(int d, int s, int t, int c) {
  return (size_t)(((d * 48 + s) * 48 + t) * 2 + c) * 8192u;  // f32 elements
}

__device__ __forceinline__ int* flagp(char* ws, size_t off, int s, int t) {
  return (int*)(ws + off) + (size_t)(s * 48 + t) * 32;  // one 128B line per cell
}

__device__ __forceinline__ void wait_ge(int* p, int v) {
  while (__hip_atomic_load(p, __ATOMIC_RELAXED, __HIP_MEMORY_SCOPE_AGENT) < v)
    __builtin_amdgcn_s_sleep(1);
  asm volatile("" ::: "memory");  // keep subsequent loads below the spin
}

// write-through to LLC (sc0 sc1): visible agent-wide once vmcnt retires.
__device__ __forceinline__ void st_llc(float* p, float v) {
  __hip_atomic_store(p, v, __ATOMIC_RELAXED, __HIP_MEMORY_SCOPE_AGENT);
}
__device__ __forceinline__ void st_llc_i(int* p, int v) {
  __hip_atomic_store(p, v, __ATOMIC_RELAXED, __HIP_MEMORY_SCOPE_AGENT);
}

__device__ __forceinline__ float fast_tanh(float x) {
  float e = exp2f(x * 2.88539008f);
  return 1.f - __fdividef(2.f, e + 1.f);
}

// ---------------------------------------------------------------------------
// Kernel 1: U (2,512,256) f32 and W (2,256,256) f32 -> bf16 MFMA B-fragments.
// Also zeroes the flag regions (bypass stores, so in-kernel pollers see them).
// ---------------------------------------------------------------------------
__global__ void preswizzle(const float* __restrict__ U,
                           const float* __restrict__ W,
                           char* __restrict__ ws) {
  int gid = blockIdx.x * 256 + threadIdx.x;
  {
    int* fz = (int*)(ws + FLAGA0_OFF);
    const int total = (int)(FLAG_BYTES / 4);
    for (int i = gid; i < total; i += 192 * 256) st_llc_i(&fz[i], 0);
  }
  if (gid < 32768) {  // U
    int r = gid >> 11;
    int d = r >> 3, nh = (r >> 2) & 1, w = r & 3;
    int c = gid & 2047;
    int f = c >> 6, lane = c & 63;
    int nt = f >> 4, ks = f & 15;
    int kbase = ks * 32 + (lane >> 4) * 8;
    int n = nh * 128 + w * 32 + nt * 16 + (lane & 15);
    const float* sp = U + (size_t)d * 512 * 256 + n;
    short8 v;
#pragma unroll
    for (int j = 0; j < 8; ++j) v[j] = f2bf(sp[(size_t)(kbase + j) * 256]);
    *(short8*)(ws + UF_OFF + (size_t)gid * 16) = v;
  } else {            // W
    int idx = gid - 32768;
    int r = idx >> 10;
    int d = r >> 3, nh = (r >> 2) & 1, w = r & 3;
    int c = idx & 1023;
    int f = c >> 6, lane = c & 63;
    int nt = f >> 3, ks = f & 7;
    int kbase = ks * 32 + (lane >> 4) * 8;
    int n = nh * 128 + w * 32 + nt * 16 + (lane & 15);
    const float* sp = W + (size_t)d * 256 * 256 + n;
    short8 v;
#pragma unroll
    for (int j = 0; j < 8; ++j) v[j] = f2bf(sp[(size_t)(kbase + j) * 256]);
    *(short8*)(ws + WF_OFF + (size_t)idx * 16) = v;
  }
}

// ---------------------------------------------------------------------------
// Kernel 2: SRCW[s] = src[s]@W0 + b0 ; TRGW[t] = trg[t]@W0 + b0  (f32),
// stored in grid_main's per-thread accumulator layout: [i][gtid][16].
// ---------------------------------------------------------------------------
__global__ __launch_bounds__(256, 1) void precompute_xw(
    const float* __restrict__ src, const float* __restrict__ trg,
    const float* __restrict__ bvec, char* __restrict__ ws) {
  __shared__ __align__(16) char lds[32 * 528];
  const int bid = blockIdx.x;
  const int i = bid >> 1, nh = bid & 1;
  const int tid = threadIdx.x;
  const int w = tid >> 6, lane = tid & 63;
  const int alane = lane & 15, q = lane >> 4;

  short8 bw[2][8];
  {
    const char* wb = ws + WF_OFF + (size_t)(nh * 4 + w) * 16384u + (size_t)lane * 16;
#pragma unroll
    for (int nt = 0; nt < 2; ++nt)
#pragma unroll
      for (int ks = 0; ks < 8; ++ks)
        bw[nt][ks] = *(const short8*)(wb + (nt * 8 + ks) * 1024);
  }

  const float* plane = (i < 48) ? src + (size_t)i * 8192 : trg + (size_t)(i - 48) * 8192;
#pragma unroll
  for (int it = 0; it < 4; ++it) {
    int gid = it * 256 + tid;
    int row = gid >> 5, c = gid & 31;
    const float* p = plane + row * 256 + c * 8;
    short8 v;
#pragma unroll
    for (int j = 0; j < 8; ++j) v[j] = f2bf(p[j]);
    *(short8*)(lds + row * 528 + c * 16) = v;
  }
  __syncthreads();

  const f32x4 zf = {0.f, 0.f, 0.f, 0.f};
  f32x4 acc[2][2];
  acc[0][0] = zf; acc[0][1] = zf; acc[1][0] = zf; acc[1][1] = zf;
  const char* ar0 = lds + alane * 528 + q * 16;
  const char* ar1 = lds + (alane + 16) * 528 + q * 16;
#pragma unroll
  for (int ks = 0; ks < 8; ++ks) {
    short8 a0 = *(const short8*)(ar0 + ks * 64);
    short8 a1 = *(const short8*)(ar1 + ks * 64);
#pragma unroll
    for (int nt = 0; nt < 2; ++nt) {
      acc[0][nt] = MFMA16(a0, bw[nt][ks], acc[0][nt]);
      acc[1][nt] = MFMA16(a1, bw[nt][ks], acc[1][nt]);
    }
  }

  const int n0 = nh * 128 + w * 32 + alane;
  float bs[2] = {bvec[n0], bvec[n0 + 16]};
  const int gtid = (nh * 4 + w) * 64 + lane;
  float* dst = (float*)(ws + (i < 48 ? SRCW_OFF : TRGW_OFF)) +
               (size_t)(i < 48 ? i : i - 48) * 8192 + (size_t)gtid * 16;
#pragma unroll
  for (int mt = 0; mt < 2; ++mt)
#pragma unroll
    for (int nt = 0; nt < 2; ++nt) {
      f32x4 v = acc[mt][nt];
      v[0] += bs[nt]; v[1] += bs[nt]; v[2] += bs[nt]; v[3] += bs[nt];
      ((f32x4*)dst)[mt * 2 + nt] = v;
    }
}

// ---------------------------------------------------------------------------
// Kernel 3: persistent systolic grid. 96 blocks x 512 threads = (d, t).
// ---------------------------------------------------------------------------
__global__ __launch_bounds__(512)
__attribute__((amdgpu_waves_per_eu(1, 2)))
void grid_main(float* __restrict__ out, const float* __restrict__ bvec,
               char* __restrict__ ws) {
  // buf0 = persistent up-image; buf1 = left/x; buf2 = y; buf3 = left1.
  __shared__ __align__(16) char lds[4 * 32 * 528];
  char* const buf0 = lds;
  char* const buf1 = lds + 32 * 528;
  char* const buf2 = lds + 2 * 32 * 528;
  char* const buf3 = lds + 3 * 32 * 528;

  const int bid = blockIdx.x;        // 96 = (d, t)
  const int d = bid / 48;
  const int t = bid % 48;
  const int tid = threadIdx.x;       // 0..511
  const int wv = tid >> 6;           // 0..7
  const int nh = wv >> 2, w = wv & 3;
  const int lane = tid & 63;
  const int alane = lane & 15, q = lane >> 4;
  const int n0 = nh * 128 + w * 32 + alane;

  const float* SRCW = (const float*)(ws + SRCW_OFF);
  const float* TRGW = (const float*)(ws + TRGW_OFF);
  const char* ubp = ws + UF_OFF + (size_t)((d * 2 + nh) * 4 + w) * 32768u +
                    (size_t)lane * 16;

  // Pin the Uy (left) fragments in registers: they sit on the post-detect
  // critical path. Ux (up) fragments stream from L2 in the poll window.
  short8 buL[2][8];
#pragma unroll
  for (int nt = 0; nt < 2; ++nt)
#pragma unroll
    for (int ks = 0; ks < 8; ++ks) {
      buL[nt][ks] = *(const short8*)(ubp + (nt * 16 + 8 + ks) * 1024);
      asm volatile("" : "+v"(buL[nt][ks]));
    }

  const char* up0 = buf0 + alane * 528 + q * 16;
  const char* up1 = buf0 + (alane + 16) * 528 + q * 16;
  const char* l0  = buf1 + alane * 528 + q * 16;
  const char* l1  = buf1 + (alane + 16) * 528 + q * 16;
  const char* y0  = buf2 + alane * 528 + q * 16;
  const char* y1  = buf2 + (alane + 16) * 528 + q * 16;
  const char* m0  = buf3 + alane * 528 + q * 16;
  const char* m1  = buf3 + (alane + 16) * 528 + q * 16;
  const f32x4 zf = {0.f, 0.f, 0.f, 0.f};

  f32x4 accTup[2][2];  // up@Ux carried from the previous cell's fused pass
  accTup[0][0] = zf; accTup[0][1] = zf; accTup[1][0] = zf; accTup[1][1] = zf;
  float hyin[16];      // deferred hy pre-activation from the previous cell

  if (d == 0) {
    f32x4 pfy[4];
    {
      const f32x4* py = (const f32x4*)(TRGW + (size_t)t * 8192 + (size_t)tid * 16);
      pfy[0] = py[0]; pfy[1] = py[1]; pfy[2] = py[2]; pfy[3] = py[3];
    }
    for (int s = 0; s < 48; ++s) {
      // ================= poll window (overlaps left neighbor's tail) =======
      if (s > 0) {  // deferred hy(s-1): tanh + bypass stores + drain + flagB
        float* hyp = out + plane_off(0, s - 1, t, 1);
#pragma unroll
        for (int mt = 0; mt < 2; ++mt)
#pragma unroll
          for (int nt = 0; nt < 2; ++nt)
#pragma unroll
            for (int rr = 0; rr < 4; ++rr) {
              int row = mt * 16 + q * 4 + rr, c = n0 + nt * 16;
              st_llc(&hyp[row * 256 + c], fast_tanh(hyin[(mt * 2 + nt) * 4 + rr]));
            }
        asm volatile("s_waitcnt vmcnt(0)" ::: "memory");
        if (lane == 0)
          __hip_atomic_fetch_add(flagp(ws, FLAGB0_OFF, s - 1, t), 1,
                                 __ATOMIC_RELAXED, __HIP_MEMORY_SCOPE_AGENT);
      }
      f32x4 sxv[4];
      {
        const f32x4* px = (const f32x4*)(SRCW + (size_t)s * 8192 + (size_t)tid * 16);
        sxv[0] = px[0]; sxv[1] = px[1]; sxv[2] = px[2]; sxv[3] = px[3];
      }
      // ================= post-detect critical path ==========================
      if (t > 0) {
        wait_ge(flagp(ws, FLAGA0_OFF, s, t - 1), 8);
        const float* pl = out + plane_off(0, s, t - 1, 0);
        f32x4 lva[2], lvb[2];
#pragma unroll
        for (int it = 0; it < 2; ++it) {
          int gid = it * 512 + tid;
          int row = gid >> 5, c = gid & 31;
          const float* p = pl + row * 256 + c * 8;
          lva[it] = *(const f32x4*)p;
          lvb[it] = *(const f32x4*)(p + 4);
        }
#pragma unroll
        for (int it = 0; it < 2; ++it) {
          int gid = it * 512 + tid;
          int row = gid >> 5, c = gid & 31;
          short8 v;
#pragma unroll
          for (int j = 0; j < 4; ++j) {
            v[j] = f2bf(lva[it][j]);
            v[4 + j] = f2bf(lvb[it][j]);
          }
          *(short8*)(buf1 + row * 528 + c * 16) = v;
        }
      }
      __syncthreads();  // B1: left staged; all waves past fused(s-1)
      f32x4 accT[2][2];
      accT[0][0] = accTup[0][0]; accT[0][1] = accTup[0][1];
      accT[1][0] = accTup[1][0]; accT[1][1] = accTup[1][1];
      if (t > 0) {
#pragma unroll
        for (int ks = 0; ks < 8; ++ks) {
          short8 a0 = *(const short8*)(l0 + ks * 64);
          short8 a1 = *(const short8*)(l1 + ks * 64);
          accT[0][0] = MFMA16(a0, buL[0][ks], accT[0][0]);
          accT[0][1] = MFMA16(a0, buL[1][ks], accT[0][1]);
          accT[1][0] = MFMA16(a1, buL[0][ks], accT[1][0]);
          accT[1][1] = MFMA16(a1, buL[1][ks], accT[1][1]);
        }
      }
      float hxv[16];
      {
        float* hxp = out + plane_off(0, s, t, 0);
#pragma unroll
        for (int mt = 0; mt < 2; ++mt)
#pragma unroll
          for (int nt = 0; nt < 2; ++nt)
#pragma unroll
            for (int rr = 0; rr < 4; ++rr) {
              int i = (mt * 2 + nt) * 4 + rr;
              int row = mt * 16 + q * 4 + rr, c = n0 + nt * 16;
              float tv = accT[mt][nt][rr];
              float xv = fast_tanh(sxv[mt * 2 + nt][rr] + tv);
              hxv[i] = xv;
              hyin[i] = pfy[mt * 2 + nt][rr] + tv;  // tanh deferred
              st_llc(&hxp[row * 256 + c], xv);
            }
      }
      asm volatile("s_waitcnt vmcnt(0)" ::: "memory");
      if (lane == 0)
        __hip_atomic_fetch_add(flagp(ws, FLAGA0_OFF, s, t), 1,
                               __ATOMIC_RELAXED, __HIP_MEMORY_SCOPE_AGENT);
#pragma unroll
      for (int mt = 0; mt < 2; ++mt)
#pragma unroll
        for (int nt = 0; nt < 2; ++nt)
#pragma unroll
          for (int rr = 0; rr < 4; ++rr) {
            int row = mt * 16 + q * 4 + rr, c = n0 + nt * 16;
            *(short*)(buf0 + row * 528 + c * 2) = f2bf(hxv[(mt * 2 + nt) * 4 + rr]);
          }
      __syncthreads();  // B2: up-image(s) complete
      // fused up-pass for s+1 (window work; Ux frags streamed from L2)
      accTup[0][0] = zf; accTup[0][1] = zf; accTup[1][0] = zf; accTup[1][1] = zf;
      if (s < 47) {
#pragma unroll
        for (int ks = 0; ks < 8; ++ks) {
          short8 b0 = *(const short8*)(ubp + (0 * 16 + ks) * 1024);
          short8 b1 = *(const short8*)(ubp + (1 * 16 + ks) * 1024);
          short8 a0 = *(const short8*)(up0 + ks * 64);
          short8 a1 = *(const short8*)(up1 + ks * 64);
          accTup[0][0] = MFMA16(a0, b0, accTup[0][0]);
          accTup[0][1] = MFMA16(a0, b1, accTup[0][1]);
          accTup[1][0] = MFMA16(a1, b0, accTup[1][0]);
          accTup[1][1] = MFMA16(a1, b1, accTup[1][1]);
        }
      }
    }
    {  // epilogue: deferred hy(47)
      float* hyp = out + plane_off(0, 47, t, 1);
#pragma unroll
      for (int mt = 0; mt < 2; ++mt)
#pragma unroll
        for (int nt = 0; nt < 2; ++nt)
#pragma unroll
          for (int rr = 0; rr < 4; ++rr) {
            int row = mt * 16 + q * 4 + rr, c = n0 + nt * 16;
            st_llc(&hyp[row * 256 + c], fast_tanh(hyin[(mt * 2 + nt) * 4 + rr]));
          }
      asm volatile("s_waitcnt vmcnt(0)" ::: "memory");
      if (lane == 0)
        __hip_atomic_fetch_add(flagp(ws, FLAGB0_OFF, 47, t), 1,
                               __ATOMIC_RELAXED, __HIP_MEMORY_SCOPE_AGENT);
    }
  } else {
    // ---- layer 1 ----
    const char* wbp = ws + WF_OFF + (size_t)((2 + nh) * 4 + w) * 16384u +
                      (size_t)lane * 16;
    const float bsa = bvec[256 + n0], bsb = bvec[256 + n0 + 16];
    const f32x4 bA = {bsa, bsa, bsa, bsa};
    const f32x4 bB = {bsb, bsb, bsb, bsb};
    for (int s = 0; s < 48; ++s) {
      // ================= window =================
      if (s > 0) {  // deferred hy1(s-1): plain cached stores (final output)
        float* hyp = out + plane_off(1, s - 1, t, 1);
#pragma unroll
        for (int mt = 0; mt < 2; ++mt)
#pragma unroll
          for (int nt = 0; nt < 2; ++nt)
#pragma unroll
            for (int rr = 0; rr < 4; ++rr) {
              int row = mt * 16 + q * 4 + rr, c = n0 + nt * 16;
              hyp[row * 256 + c] = fast_tanh(hyin[(mt * 2 + nt) * 4 + rr]);
            }
      }
      wait_ge(flagp(ws, FLAGB0_OFF, s, t), 8);  // hy0 drained => hx0 too
      {
        const float* px = out + plane_off(0, s, t, 0);
        const float* py = out + plane_off(0, s, t, 1);
        f32x4 xva[4], xvb[4];
#pragma unroll
        for (int it = 0; it < 4; ++it) {
          int gid = it * 512 + tid;
          int pidx = gid >> 10, row = (gid >> 5) & 31, c = gid & 31;
          const float* pp = (pidx ? py : px) + row * 256 + c * 8;
          xva[it] = *(const f32x4*)pp;
          xvb[it] = *(const f32x4*)(pp + 4);
        }
#pragma unroll
        for (int it = 0; it < 4; ++it) {
          int gid = it * 512 + tid;
          int pidx = gid >> 10, row = (gid >> 5) & 31, c = gid & 31;
          char* db = pidx ? buf2 : buf1;
          short8 v;
#pragma unroll
          for (int j = 0; j < 4; ++j) {
            v[j] = f2bf(xva[it][j]);
            v[4 + j] = f2bf(xvb[it][j]);
          }
          *(short8*)(db + row * 528 + c * 16) = v;
        }
      }
      __syncthreads();  // B0w: x/y staged
      f32x4 accx[2][2], accy[2][2];
      accx[0][0] = bA; accx[0][1] = bB; accx[1][0] = bA; accx[1][1] = bB;
      accy[0][0] = bA; accy[0][1] = bB; accy[1][0] = bA; accy[1][1] = bB;
#pragma unroll
      for (int ks = 0; ks < 8; ++ks) {
        short8 b0 = *(const short8*)(wbp + ks * 1024);
        short8 b1 = *(const short8*)(wbp + (8 + ks) * 1024);
        short8 ax0 = *(const short8*)(l0 + ks * 64);
        short8 ax1 = *(const short8*)(l1 + ks * 64);
        short8 ay0 = *(const short8*)(y0 + ks * 64);
        short8 ay1 = *(const short8*)(y1 + ks * 64);
        accx[0][0] = MFMA16(ax0, b0, accx[0][0]);
        accx[0][1] = MFMA16(ax0, b1, accx[0][1]);
        accx[1][0] = MFMA16(ax1, b0, accx[1][0]);
        accx[1][1] = MFMA16(ax1, b1, accx[1][1]);
        accy[0][0] = MFMA16(ay0, b0, accy[0][0]);
        accy[0][1] = MFMA16(ay0, b1, accy[0][1]);
        accy[1][0] = MFMA16(ay1, b0, accy[1][0]);
        accy[1][1] = MFMA16(ay1, b1, accy[1][1]);
      }
      // ================= post-detect =================
      if (t > 0) {
        wait_ge(flagp(ws, FLAGA1_OFF, s, t - 1), 8);
        const float* pl = out + plane_off(1, s, t - 1, 0);
        f32x4 lva[2], lvb[2];
#pragma unroll
        for (int it = 0; it < 2; ++it) {
          int gid = it * 512 + tid;
          int row = gid >> 5, c = gid & 31;
          const float* p = pl + row * 256 + c * 8;
          lva[it] = *(const f32x4*)p;
          lvb[it] = *(const f32x4*)(p + 4);
        }
#pragma unroll
        for (int it = 0; it < 2; ++it) {
          int gid = it * 512 + tid;
          int row = gid >> 5, c = gid & 31;
          short8 v;
#pragma unroll
          for (int j = 0; j < 4; ++j) {
            v[j] = f2bf(lva[it][j]);
            v[4 + j] = f2bf(lvb[it][j]);
          }
          *(short8*)(buf3 + row * 528 + c * 16) = v;
        }
      }
      __syncthreads();  // B1: left1 staged; all waves past xy-MFMA and fused
      f32x4 accT[2][2];
      accT[0][0] = accTup[0][0]; accT[0][1] = accTup[0][1];
      accT[1][0] = accTup[1][0]; accT[1][1] = accTup[1][1];
      if (t > 0) {
#pragma unroll
        for (int ks = 0; ks < 8; ++ks) {
          short8 a0 = *(const short8*)(m0 + ks * 64);
          short8 a1 = *(const short8*)(m1 + ks * 64);
          accT[0][0] = MFMA16(a0, buL[0][ks], accT[0][0]);
          accT[0][1] = MFMA16(a0, buL[1][ks], accT[0][1]);
          accT[1][0] = MFMA16(a1, buL[0][ks], accT[1][0]);
          accT[1][1] = MFMA16(a1, buL[1][ks], accT[1][1]);
        }
      }
      float hxv[16];
      {
        float* hxp = out + plane_off(1, s, t, 0);
#pragma unroll
        for (int mt = 0; mt < 2; ++mt)
#pragma unroll
          for (int nt = 0; nt < 2; ++nt)
#pragma unroll
            for (int rr = 0; rr < 4; ++rr) {
              int i = (mt * 2 + nt) * 4 + rr;
              int row = mt * 16 + q * 4 + rr, c = n0 + nt * 16;
              float tv = accT[mt][nt][rr];
              float xv = fast_tanh(accx[mt][nt][rr] + tv);
              hxv[i] = xv;
              hyin[i] = accy[mt][nt][rr] + tv;  // tanh deferred
              st_llc(&hxp[row * 256 + c], xv);
            }
      }
      asm volatile("s_waitcnt vmcnt(0)" ::: "memory");
      if (lane == 0)
        __hip_atomic_fetch_add(flagp(ws, FLAGA1_OFF, s, t), 1,
                               __ATOMIC_RELAXED, __HIP_MEMORY_SCOPE_AGENT);
#pragma unroll
      for (int mt = 0; mt < 2; ++mt)
#pragma unroll
        for (int nt = 0; nt < 2; ++nt)
#pragma unroll
          for (int rr = 0; rr < 4; ++rr) {
            int row = mt * 16 + q * 4 + rr, c = n0 + nt * 16;
            *(short*)(buf0 + row * 528 + c * 2) = f2bf(hxv[(mt * 2 + nt) * 4 + rr]);
          }
      __syncthreads();  // B2
      accTup[0][0] = zf; accTup[0][1] = zf; accTup[1][0] = zf; accTup[1][1] = zf;
      if (s < 47) {
#pragma unroll
        for (int ks = 0; ks < 8; ++ks) {
          short8 b0 = *(const short8*)(ubp + (0 * 16 + ks) * 1024);
          short8 b1 = *(const short8*)(ubp + (1 * 16 + ks) * 1024);
          short8 a0 = *(const short8*)(up0 + ks * 64);
          short8 a1 = *(const short8*)(up1 + ks * 64);
          accTup[0][0] = MFMA16(a0, b0, accTup[0][0]);
          accTup[0][1] = MFMA16(a0, b1, accTup[0][1]);
          accTup[1][0] = MFMA16(a1, b0, accTup[1][0]);
          accTup[1][1] = MFMA16(a1, b1, accTup[1][1]);
        }
      }
    }
    {  // epilogue: deferred hy1(47)
      float* hyp = out + plane_off(1, 47, t, 1);
#pragma unroll
      for (int mt = 0; mt < 2; ++mt)
#pragma unroll
        for (int nt = 0; nt < 2; ++nt)
#pragma unroll
          for (int rr = 0; rr < 4; ++rr) {
            int row = mt * 16 + q * 4 + rr, c = n0 + nt * 16;
            hyp[row * 256 + c] = fast_tanh(hyin[(mt * 2 + nt) * 4 + rr]);
          }
    }
  }
}

extern "C" void kernel_launch(void* const* d_in, const int* in_sizes, int n_in,
                              void* d_out, int out_size, void* d_ws, size_t ws_size,
                              hipStream_t stream) {
  const float* src = (const float*)d_in[0];
  const float* trg = (const float*)d_in[1];
  const float* W   = (const float*)d_in[2];
  const float* U   = (const float*)d_in[3];
  const float* bv  = (const float*)d_in[4];
  float* out = (float*)d_out;
  char* ws = (char*)d_ws;

  preswizzle<<<192, 256, 0, stream>>>(U, W, ws);   // also zeroes flags
  precompute_xw<<<192, 256, 0, stream>>>(src, trg, bv, ws);
  grid_main<<<96, 512, 0, stream>>>(out, bv, ws);
}